// Round 1
// baseline (530.360 us; speedup 1.0000x reference)
//
#include <hip/hip_runtime.h>
#include <hip/hip_bf16.h>

#define D 128            // D_IN == D_OUT
#define D2 64            // D/2 (float2 elements per row)

// ---------------------------------------------------------------------------
// Kernel 1: y = x @ W   (fp32, vector ALU)
// thread -> (row r, 4 consecutive cols jg). 32 threads cover one row's cols.
// ---------------------------------------------------------------------------
__global__ __launch_bounds__(256) void gemm_xw_kernel(
    const float* __restrict__ x, const float* __restrict__ W,
    float* __restrict__ y, int n_nodes)
{
    int gid = blockIdx.x * blockDim.x + threadIdx.x;
    int r  = gid >> 5;            // row
    int jg = (gid & 31) << 2;     // col group of 4
    if (r >= n_nodes) return;

    const float* xr = x + (size_t)r * D;
    float4 acc = make_float4(0.f, 0.f, 0.f, 0.f);
#pragma unroll 8
    for (int k = 0; k < D; ++k) {
        float xv = xr[k];
        const float4 w = *reinterpret_cast<const float4*>(W + (size_t)k * D + jg);
        acc.x += xv * w.x;
        acc.y += xv * w.y;
        acc.z += xv * w.z;
        acc.w += xv * w.w;
    }
    *reinterpret_cast<float4*>(y + (size_t)r * D + jg) = acc;
}

// ---------------------------------------------------------------------------
// Kernel 2: build CSR row_ptr from sorted edge_row.
// ptr[r] = lower_bound(edge_row, r).  Launch E+1 threads.
// ---------------------------------------------------------------------------
__global__ __launch_bounds__(256) void build_rowptr_kernel(
    const int* __restrict__ row, int* __restrict__ ptr, int n_edges, int n_nodes)
{
    int e = blockIdx.x * blockDim.x + threadIdx.x;
    if (e > n_edges) return;
    int lo, hi;                     // set ptr[r] = e for r in (lo, hi]
    if (e == 0)            { lo = -1;              hi = row[0];   }
    else if (e == n_edges) { lo = row[n_edges - 1]; hi = n_nodes; }
    else {
        lo = row[e - 1];
        hi = row[e];
        if (lo == hi) return;
    }
    for (int r = lo + 1; r <= hi; ++r) ptr[r] = e;
}

// ---------------------------------------------------------------------------
// Kernel 3: out[r,:] = sum_{e in [ptr[r],ptr[r+1])} val[e] * y[col[e],:]
// One wave (64 lanes) per row; each lane owns a float2 (2 columns).
// No atomics, direct store (rows are disjoint across waves).
// ---------------------------------------------------------------------------
__global__ __launch_bounds__(256) void spmm_kernel(
    const float2* __restrict__ y2, const int* __restrict__ ptr,
    const int* __restrict__ col, const float* __restrict__ val,
    float2* __restrict__ out2, int n_nodes)
{
    int gid  = blockIdx.x * blockDim.x + threadIdx.x;
    int r    = gid >> 6;            // one wave per row
    int lane = threadIdx.x & 63;
    if (r >= n_nodes) return;

    int s = ptr[r];
    int e = ptr[r + 1];
    float2 acc = make_float2(0.f, 0.f);
    for (int i = s; i < e; ++i) {
        int   c = col[i];
        float v = val[i];
        float2 m = y2[(size_t)c * D2 + lane];
        acc.x += v * m.x;
        acc.y += v * m.y;
    }
    out2[(size_t)r * D2 + lane] = acc;
}

// ---------------------------------------------------------------------------
extern "C" void kernel_launch(void* const* d_in, const int* in_sizes, int n_in,
                              void* d_out, int out_size, void* d_ws, size_t ws_size,
                              hipStream_t stream)
{
    const float* x        = (const float*)d_in[0];
    const int*   edge_row = (const int*)  d_in[1];
    const int*   edge_col = (const int*)  d_in[2];
    const float* edge_val = (const float*)d_in[3];
    const float* W        = (const float*)d_in[4];
    float*       out      = (float*)d_out;

    const int n_nodes = in_sizes[0] / D;
    const int n_edges = in_sizes[1];

    // workspace layout: y [n_nodes*D f32] | row_ptr [(n_nodes+1) i32]
    float* y   = (float*)d_ws;
    int*   ptr = (int*)((char*)d_ws + (size_t)n_nodes * D * sizeof(float));

    // 1) y = x @ W
    {
        int total  = n_nodes * 32;               // 32 threads per row
        int blocks = (total + 255) / 256;
        gemm_xw_kernel<<<blocks, 256, 0, stream>>>(x, W, y, n_nodes);
    }
    // 2) row_ptr
    {
        int blocks = (n_edges + 1 + 255) / 256;
        build_rowptr_kernel<<<blocks, 256, 0, stream>>>(edge_row, ptr, n_edges, n_nodes);
    }
    // 3) out = A @ y   (one wave per row)
    {
        int rows_per_block = 256 / 64;
        int blocks = (n_nodes + rows_per_block - 1) / rows_per_block;
        spmm_kernel<<<blocks, 256, 0, stream>>>((const float2*)y, ptr,
                                                edge_col, edge_val,
                                                (float2*)out, n_nodes);
    }
}

// Round 2
// 204.550 us; speedup vs baseline: 2.5928x; 2.5928x over previous
//
#include <hip/hip_runtime.h>
#include <hip/hip_bf16.h>

#define D 128            // D_IN == D_OUT
#define D2U 64           // D/2 packed bf16 pairs (uint) per row

// ---------------------------------------------------------------------------
// fp32 -> bf16 (round-to-nearest-even), returns high 16 bits
// ---------------------------------------------------------------------------
__device__ __forceinline__ unsigned int f2bf(float f) {
    unsigned int u = __float_as_uint(f);
    u += 0x7FFFu + ((u >> 16) & 1u);
    return u >> 16;
}

// ---------------------------------------------------------------------------
// Kernel 1: y = bf16(x @ W)   (fp32 vector ALU, register-blocked 4x8)
// Block = 256 threads -> 64 rows. Thread (tr,tc): rows blk*64+tr*4..+3,
// cols tc*8..+7. k unrolled by 4 with float4 x loads.
// y packed as uint: low16 = bf16(col even), high16 = bf16(col odd).
// ---------------------------------------------------------------------------
__global__ __launch_bounds__(256) void gemm_xw_kernel(
    const float* __restrict__ x, const float* __restrict__ W,
    unsigned int* __restrict__ y, int n_nodes)
{
    const int tr = threadIdx.x >> 4;        // 0..15
    const int tc = threadIdx.x & 15;        // 0..15
    const int r0 = blockIdx.x * 64 + tr * 4;
    const int jg = tc * 8;

    float acc[4][8];
#pragma unroll
    for (int i = 0; i < 4; ++i)
#pragma unroll
        for (int j = 0; j < 8; ++j) acc[i][j] = 0.f;

    // clamp row pointers for safe loads; OOB rows masked at store
    const float* xp[4];
#pragma unroll
    for (int i = 0; i < 4; ++i) {
        int r = r0 + i;
        xp[i] = x + (size_t)(r < n_nodes ? r : n_nodes - 1) * D;
    }

    for (int k0 = 0; k0 < D; k0 += 4) {
        float4 xv[4];
#pragma unroll
        for (int i = 0; i < 4; ++i)
            xv[i] = *reinterpret_cast<const float4*>(xp[i] + k0);
#pragma unroll
        for (int kk = 0; kk < 4; ++kk) {
            const float4 w0 = *reinterpret_cast<const float4*>(W + (size_t)(k0 + kk) * D + jg);
            const float4 w1 = *reinterpret_cast<const float4*>(W + (size_t)(k0 + kk) * D + jg + 4);
            const float wj[8] = {w0.x, w0.y, w0.z, w0.w, w1.x, w1.y, w1.z, w1.w};
#pragma unroll
            for (int i = 0; i < 4; ++i) {
                const float xs = (kk == 0) ? xv[i].x : (kk == 1) ? xv[i].y
                               : (kk == 2) ? xv[i].z : xv[i].w;
#pragma unroll
                for (int j = 0; j < 8; ++j) acc[i][j] += xs * wj[j];
            }
        }
    }

#pragma unroll
    for (int i = 0; i < 4; ++i) {
        int r = r0 + i;
        if (r >= n_nodes) break;
        uint4 pk;
        pk.x = f2bf(acc[i][0]) | (f2bf(acc[i][1]) << 16);
        pk.y = f2bf(acc[i][2]) | (f2bf(acc[i][3]) << 16);
        pk.z = f2bf(acc[i][4]) | (f2bf(acc[i][5]) << 16);
        pk.w = f2bf(acc[i][6]) | (f2bf(acc[i][7]) << 16);
        *reinterpret_cast<uint4*>(y + (size_t)r * D2U + (jg >> 1)) = pk;
    }
}

// ---------------------------------------------------------------------------
// Kernel 2: build CSR row_ptr from sorted edge_row.
// ---------------------------------------------------------------------------
__global__ __launch_bounds__(256) void build_rowptr_kernel(
    const int* __restrict__ row, int* __restrict__ ptr, int n_edges, int n_nodes)
{
    int e = blockIdx.x * blockDim.x + threadIdx.x;
    if (e > n_edges) return;
    int lo, hi;                     // set ptr[r] = e for r in (lo, hi]
    if (e == 0)            { lo = -1;               hi = row[0];   }
    else if (e == n_edges) { lo = row[n_edges - 1]; hi = n_nodes;  }
    else {
        lo = row[e - 1];
        hi = row[e];
        if (lo == hi) return;
    }
    for (int r = lo + 1; r <= hi; ++r) ptr[r] = e;
}

// ---------------------------------------------------------------------------
// Kernel 3: out[r,:] = sum_e val[e] * y[col[e],:]   (bf16 gather, fp32 acc)
// One wave per row, lane owns 1 packed uint (2 cols). Edge loop unrolled x4
// with independent gathers for MLP. Row bounds made wave-uniform so col/val
// go through the scalar path.
// ---------------------------------------------------------------------------
__device__ __forceinline__ float bflo(unsigned int u) { return __uint_as_float(u << 16); }
__device__ __forceinline__ float bfhi(unsigned int u) { return __uint_as_float(u & 0xFFFF0000u); }

__global__ __launch_bounds__(256) void spmm_kernel(
    const unsigned int* __restrict__ yb, const int* __restrict__ ptr,
    const int* __restrict__ col, const float* __restrict__ val,
    float2* __restrict__ out2, int n_nodes)
{
    int gid  = blockIdx.x * blockDim.x + threadIdx.x;
    int r    = gid >> 6;            // one wave per row (uniform across wave)
    int lane = threadIdx.x & 63;
    if (r >= n_nodes) return;

    const int s = __builtin_amdgcn_readfirstlane(ptr[r]);
    const int e = __builtin_amdgcn_readfirstlane(ptr[r + 1]);

    float ax = 0.f, ay = 0.f;
    int i = s;
    for (; i + 4 <= e; i += 4) {
        const int   c0 = col[i],     c1 = col[i + 1], c2 = col[i + 2], c3 = col[i + 3];
        const float v0 = val[i],     v1 = val[i + 1], v2 = val[i + 2], v3 = val[i + 3];
        const unsigned int u0 = yb[(size_t)c0 * D2U + lane];
        const unsigned int u1 = yb[(size_t)c1 * D2U + lane];
        const unsigned int u2 = yb[(size_t)c2 * D2U + lane];
        const unsigned int u3 = yb[(size_t)c3 * D2U + lane];
        ax += v0 * bflo(u0); ay += v0 * bfhi(u0);
        ax += v1 * bflo(u1); ay += v1 * bfhi(u1);
        ax += v2 * bflo(u2); ay += v2 * bfhi(u2);
        ax += v3 * bflo(u3); ay += v3 * bfhi(u3);
    }
    for (; i < e; ++i) {
        const int   c = col[i];
        const float v = val[i];
        const unsigned int u = yb[(size_t)c * D2U + lane];
        ax += v * bflo(u); ay += v * bfhi(u);
    }
    out2[(size_t)r * D2U + lane] = make_float2(ax, ay);
}

// ---------------------------------------------------------------------------
extern "C" void kernel_launch(void* const* d_in, const int* in_sizes, int n_in,
                              void* d_out, int out_size, void* d_ws, size_t ws_size,
                              hipStream_t stream)
{
    const float* x        = (const float*)d_in[0];
    const int*   edge_row = (const int*)  d_in[1];
    const int*   edge_col = (const int*)  d_in[2];
    const float* edge_val = (const float*)d_in[3];
    const float* W        = (const float*)d_in[4];
    float*       out      = (float*)d_out;

    const int n_nodes = in_sizes[0] / D;
    const int n_edges = in_sizes[1];

    // workspace layout: y_bf16 [n_nodes*D2U uint] | row_ptr [(n_nodes+1) i32]
    unsigned int* y   = (unsigned int*)d_ws;
    int*          ptr = (int*)((char*)d_ws + (size_t)n_nodes * D2U * sizeof(unsigned int));

    // 1) y = bf16(x @ W)
    {
        int blocks = (n_nodes + 63) / 64;
        gemm_xw_kernel<<<blocks, 256, 0, stream>>>(x, W, y, n_nodes);
    }
    // 2) row_ptr
    {
        int blocks = (n_edges + 1 + 255) / 256;
        build_rowptr_kernel<<<blocks, 256, 0, stream>>>(edge_row, ptr, n_edges, n_nodes);
    }
    // 3) out = A @ y   (one wave per row)
    {
        int rows_per_block = 256 / 64;
        int blocks = (n_nodes + rows_per_block - 1) / rows_per_block;
        spmm_kernel<<<blocks, 256, 0, stream>>>(y, ptr, edge_col, edge_val,
                                                (float2*)out, n_nodes);
    }
}

// Round 3
// 177.408 us; speedup vs baseline: 2.9895x; 1.1530x over previous
//
#include <hip/hip_runtime.h>
#include <hip/hip_bf16.h>

#define D 128            // D_IN == D_OUT
#define D2U 64           // D/2 packed bf16 pairs (uint) per row

// ---------------------------------------------------------------------------
// fp32 -> bf16 (round-to-nearest-even), returns high 16 bits
// ---------------------------------------------------------------------------
__device__ __forceinline__ unsigned int f2bf(float f) {
    unsigned int u = __float_as_uint(f);
    u += 0x7FFFu + ((u >> 16) & 1u);
    return u >> 16;
}
__device__ __forceinline__ float bflo(unsigned int u) { return __uint_as_float(u << 16); }
__device__ __forceinline__ float bfhi(unsigned int u) { return __uint_as_float(u & 0xFFFF0000u); }

// ---------------------------------------------------------------------------
// Kernel 1: y = bf16(x @ W)   (fp32 vector ALU, register-blocked 4x8)
// Block = 512 threads -> 128 rows. W staged in LDS (64 kB -> 2 blocks/CU).
// Thread (tr,tc): rows blk*128+tr*4..+3, cols tc*8..+7.
// ---------------------------------------------------------------------------
__global__ __launch_bounds__(512) void gemm_xw_kernel(
    const float* __restrict__ x, const float* __restrict__ W,
    unsigned int* __restrict__ y, int n_nodes)
{
    __shared__ float Ws[D * D];            // 64 kB

    // stage W: 512 threads x 8 x float4 = 64 kB, coalesced
    {
        const int t = threadIdx.x;
#pragma unroll
        for (int m = 0; m < 8; ++m) {
            const int idx = (m * 512 + t) * 4;
            *reinterpret_cast<float4*>(&Ws[idx]) =
                *reinterpret_cast<const float4*>(&W[idx]);
        }
    }
    __syncthreads();

    const int tr = threadIdx.x >> 4;        // 0..31
    const int tc = threadIdx.x & 15;        // 0..15
    const int r0 = blockIdx.x * 128 + tr * 4;
    const int jg = tc * 8;

    float acc[4][8];
#pragma unroll
    for (int i = 0; i < 4; ++i)
#pragma unroll
        for (int j = 0; j < 8; ++j) acc[i][j] = 0.f;

    // clamp row pointers for safe loads; OOB rows masked at store
    const float* xp[4];
#pragma unroll
    for (int i = 0; i < 4; ++i) {
        int r = r0 + i;
        xp[i] = x + (size_t)(r < n_nodes ? r : n_nodes - 1) * D;
    }

    for (int k0 = 0; k0 < D; k0 += 4) {
        float4 xv[4];
#pragma unroll
        for (int i = 0; i < 4; ++i)
            xv[i] = *reinterpret_cast<const float4*>(xp[i] + k0);
#pragma unroll
        for (int kk = 0; kk < 4; ++kk) {
            const float4 w0 = *reinterpret_cast<const float4*>(&Ws[(k0 + kk) * D + jg]);
            const float4 w1 = *reinterpret_cast<const float4*>(&Ws[(k0 + kk) * D + jg + 4]);
            const float wj[8] = {w0.x, w0.y, w0.z, w0.w, w1.x, w1.y, w1.z, w1.w};
#pragma unroll
            for (int i = 0; i < 4; ++i) {
                const float xs = (kk == 0) ? xv[i].x : (kk == 1) ? xv[i].y
                               : (kk == 2) ? xv[i].z : xv[i].w;
#pragma unroll
                for (int j = 0; j < 8; ++j) acc[i][j] += xs * wj[j];
            }
        }
    }

#pragma unroll
    for (int i = 0; i < 4; ++i) {
        int r = r0 + i;
        if (r >= n_nodes) break;
        uint4 pk;
        pk.x = f2bf(acc[i][0]) | (f2bf(acc[i][1]) << 16);
        pk.y = f2bf(acc[i][2]) | (f2bf(acc[i][3]) << 16);
        pk.z = f2bf(acc[i][4]) | (f2bf(acc[i][5]) << 16);
        pk.w = f2bf(acc[i][6]) | (f2bf(acc[i][7]) << 16);
        *reinterpret_cast<uint4*>(y + (size_t)r * D2U + (jg >> 1)) = pk;
    }
}

// ---------------------------------------------------------------------------
// Kernel 2: build CSR row_ptr from sorted edge_row.
// ---------------------------------------------------------------------------
__global__ __launch_bounds__(256) void build_rowptr_kernel(
    const int* __restrict__ row, int* __restrict__ ptr, int n_edges, int n_nodes)
{
    int e = blockIdx.x * blockDim.x + threadIdx.x;
    if (e > n_edges) return;
    int lo, hi;                     // set ptr[r] = e for r in (lo, hi]
    if (e == 0)            { lo = -1;               hi = row[0];   }
    else if (e == n_edges) { lo = row[n_edges - 1]; hi = n_nodes;  }
    else {
        lo = row[e - 1];
        hi = row[e];
        if (lo == hi) return;
    }
    for (int r = lo + 1; r <= hi; ++r) ptr[r] = e;
}

// ---------------------------------------------------------------------------
// Kernel 3: out[r,:] = sum_e val[e] * y[col[e],:]   (bf16 gather, fp32 acc)
// One wave per row, lane owns 1 packed uint (2 cols).
// 16-edge batches: col/val prefetched one batch ahead (wave-uniform scalar
// loads); 16 independent gathers in flight per wave for MLP.
// ---------------------------------------------------------------------------
#define EUNR 16

__global__ __launch_bounds__(256) void spmm_kernel(
    const unsigned int* __restrict__ yb, const int* __restrict__ ptr,
    const int* __restrict__ col, const float* __restrict__ val,
    float2* __restrict__ out2, int n_nodes)
{
    int gid  = blockIdx.x * blockDim.x + threadIdx.x;
    int r    = gid >> 6;            // one wave per row (uniform across wave)
    int lane = threadIdx.x & 63;
    if (r >= n_nodes) return;

    const int s = __builtin_amdgcn_readfirstlane(ptr[r]);
    const int e = __builtin_amdgcn_readfirstlane(ptr[r + 1]);

    float ax = 0.f, ay = 0.f;
    int i = s;

    if (i + EUNR <= e) {
        int   c[EUNR];
        float v[EUNR];
#pragma unroll
        for (int k = 0; k < EUNR; ++k) { c[k] = col[i + k]; v[k] = val[i + k]; }

        while (true) {
            unsigned int u[EUNR];
#pragma unroll
            for (int k = 0; k < EUNR; ++k)
                u[k] = yb[(size_t)c[k] * D2U + lane];

            const int  ni   = i + EUNR;
            const bool more = (ni + EUNR <= e);

            int   nc[EUNR];
            float nv[EUNR];
            if (more) {
#pragma unroll
                for (int k = 0; k < EUNR; ++k) { nc[k] = col[ni + k]; nv[k] = val[ni + k]; }
            }

#pragma unroll
            for (int k = 0; k < EUNR; ++k) {
                ax += v[k] * bflo(u[k]);
                ay += v[k] * bfhi(u[k]);
            }

            i = ni;
            if (!more) break;
#pragma unroll
            for (int k = 0; k < EUNR; ++k) { c[k] = nc[k]; v[k] = nv[k]; }
        }
    }

    // tail: 4-unrolled then scalar
    for (; i + 4 <= e; i += 4) {
        const int   c0 = col[i],     c1 = col[i + 1], c2 = col[i + 2], c3 = col[i + 3];
        const float v0 = val[i],     v1 = val[i + 1], v2 = val[i + 2], v3 = val[i + 3];
        const unsigned int u0 = yb[(size_t)c0 * D2U + lane];
        const unsigned int u1 = yb[(size_t)c1 * D2U + lane];
        const unsigned int u2 = yb[(size_t)c2 * D2U + lane];
        const unsigned int u3 = yb[(size_t)c3 * D2U + lane];
        ax += v0 * bflo(u0); ay += v0 * bfhi(u0);
        ax += v1 * bflo(u1); ay += v1 * bfhi(u1);
        ax += v2 * bflo(u2); ay += v2 * bfhi(u2);
        ax += v3 * bflo(u3); ay += v3 * bfhi(u3);
    }
    for (; i < e; ++i) {
        const int   c = col[i];
        const float v = val[i];
        const unsigned int u = yb[(size_t)c * D2U + lane];
        ax += v * bflo(u); ay += v * bfhi(u);
    }

    out2[(size_t)r * D2U + lane] = make_float2(ax, ay);
}

// ---------------------------------------------------------------------------
extern "C" void kernel_launch(void* const* d_in, const int* in_sizes, int n_in,
                              void* d_out, int out_size, void* d_ws, size_t ws_size,
                              hipStream_t stream)
{
    const float* x        = (const float*)d_in[0];
    const int*   edge_row = (const int*)  d_in[1];
    const int*   edge_col = (const int*)  d_in[2];
    const float* edge_val = (const float*)d_in[3];
    const float* W        = (const float*)d_in[4];
    float*       out      = (float*)d_out;

    const int n_nodes = in_sizes[0] / D;
    const int n_edges = in_sizes[1];

    // workspace layout: y_bf16 [n_nodes*D2U uint] | row_ptr [(n_nodes+1) i32]
    unsigned int* y   = (unsigned int*)d_ws;
    int*          ptr = (int*)((char*)d_ws + (size_t)n_nodes * D2U * sizeof(unsigned int));

    // 1) y = bf16(x @ W)
    {
        int blocks = (n_nodes + 127) / 128;
        gemm_xw_kernel<<<blocks, 512, 0, stream>>>(x, W, y, n_nodes);
    }
    // 2) row_ptr
    {
        int blocks = (n_edges + 1 + 255) / 256;
        build_rowptr_kernel<<<blocks, 256, 0, stream>>>(edge_row, ptr, n_edges, n_nodes);
    }
    // 3) out = A @ y   (one wave per row)
    {
        int rows_per_block = 256 / 64;
        int blocks = (n_nodes + rows_per_block - 1) / rows_per_block;
        spmm_kernel<<<blocks, 256, 0, stream>>>(y, ptr, edge_col, edge_val,
                                                (float2*)out, n_nodes);
    }
}

// Round 4
// 163.434 us; speedup vs baseline: 3.2451x; 1.0855x over previous
//
#include <hip/hip_runtime.h>
#include <hip/hip_bf16.h>

#define D 128            // D_IN == D_OUT
#define D2U 64           // D/2 packed bf16 pairs (uint) per row

typedef __attribute__((ext_vector_type(8))) short  short8;
typedef __attribute__((ext_vector_type(4))) float  f32x4;
typedef __attribute__((ext_vector_type(2))) float  f32x2;

// fp32 -> bf16 (RTNE)
__device__ __forceinline__ unsigned f2bf(float f) {
    unsigned u = __float_as_uint(f);
    u += 0x7FFFu + ((u >> 16) & 1u);
    return u >> 16;
}
__device__ __forceinline__ unsigned pk2(float a, float b) {
    return f2bf(a) | (f2bf(b) << 16);
}
__device__ __forceinline__ float bflo(unsigned u) { return __uint_as_float(u << 16); }
__device__ __forceinline__ float bfhi(unsigned u) { return __uint_as_float(u & 0xFFFF0000u); }

// ---------------------------------------------------------------------------
// Kernel 1: y = bf16(x @ W) via MFMA 16x16x32 bf16.
// A = W^T tile (16 W-cols x 32 k) from LDS (transposed+swizzled once/block,
// then hoisted to 128 VGPRs). B = x^T tile (32 k x 16 x-rows) direct from
// global. D[wcol][xrow] -> lane holds 4 consecutive cols of one row.
// ---------------------------------------------------------------------------
__global__ __launch_bounds__(256, 2) void gemm_mfma_kernel(
    const float* __restrict__ x, const float* __restrict__ W,
    unsigned* __restrict__ y, int n_nodes, int ntiles)
{
    __shared__ unsigned short Wt[D * D];   // bf16 [c][k], k XOR-swizzled, 32 KB

    const int t = threadIdx.x;

    // ---- transpose W fp32 [k][c] -> Wt bf16 [c][k] (slot = (k>>3) ^ (c&15))
    {
        const float4* W4 = reinterpret_cast<const float4*>(W);
#pragma unroll
        for (int m = 0; m < 16; ++m) {
            const int idx4 = m * 256 + t;        // float4 index
            const int k  = idx4 >> 5;            // 32 float4 per k-row
            const int c0 = (idx4 & 31) << 2;
            const float4 w = W4[idx4];
            const float wv[4] = {w.x, w.y, w.z, w.w};
#pragma unroll
            for (int i = 0; i < 4; ++i) {
                const int c    = c0 + i;
                const int slot = (k >> 3) ^ (c & 15);
                Wt[c * 128 + slot * 8 + (k & 7)] = (unsigned short)f2bf(wv[i]);
            }
        }
    }
    __syncthreads();

    const int lane = t & 63;
    const int cl   = lane & 15;
    const int g    = lane >> 4;

    // ---- hoist all W fragments (8 col-tiles x 4 k-steps) into registers
    short8 wf[8][4];
#pragma unroll
    for (int ct = 0; ct < 8; ++ct)
#pragma unroll
        for (int ks = 0; ks < 4; ++ks) {
            const int c    = ct * 16 + cl;
            const int slot = (ks * 4 + g) ^ cl;
            wf[ct][ks] = *reinterpret_cast<const short8*>(&Wt[c * 128 + slot * 8]);
        }

    const int wave   = (blockIdx.x << 2) | (t >> 6);
    const int nwaves = gridDim.x << 2;

#define LOADX(rt_, buf_)                                                      \
    {                                                                         \
        int r_ = (rt_) * 16 + cl;                                             \
        if (r_ >= n_nodes) r_ = n_nodes - 1;                                  \
        const float* p_ = x + (size_t)r_ * D + g * 8;                         \
        _Pragma("unroll")                                                     \
        for (int ks_ = 0; ks_ < 4; ++ks_) {                                   \
            buf_[2 * ks_]     = *reinterpret_cast<const float4*>(p_ + ks_ * 32);     \
            buf_[2 * ks_ + 1] = *reinterpret_cast<const float4*>(p_ + ks_ * 32 + 4); \
        }                                                                     \
    }

#define COMPUTE(rt_, buf_)                                                    \
    {                                                                         \
        f32x4 acc_[8];                                                        \
        _Pragma("unroll")                                                     \
        for (int ct_ = 0; ct_ < 8; ++ct_) acc_[ct_] = (f32x4)(0.f);           \
        _Pragma("unroll")                                                     \
        for (int ks_ = 0; ks_ < 4; ++ks_) {                                   \
            short8 xf_;                                                       \
            unsigned* xu_ = reinterpret_cast<unsigned*>(&xf_);                \
            const float4 a_ = buf_[2 * ks_], b_ = buf_[2 * ks_ + 1];          \
            xu_[0] = pk2(a_.x, a_.y); xu_[1] = pk2(a_.z, a_.w);               \
            xu_[2] = pk2(b_.x, b_.y); xu_[3] = pk2(b_.z, b_.w);               \
            _Pragma("unroll")                                                 \
            for (int ct_ = 0; ct_ < 8; ++ct_)                                 \
                acc_[ct_] = __builtin_amdgcn_mfma_f32_16x16x32_bf16(          \
                    wf[ct_][ks_], xf_, acc_[ct_], 0, 0, 0);                   \
        }                                                                     \
        const int r_ = (rt_) * 16 + cl;                                       \
        if (r_ < n_nodes) {                                                   \
            unsigned* yp_ = y + (size_t)r_ * D2U + g * 2;                     \
            _Pragma("unroll")                                                 \
            for (int ct_ = 0; ct_ < 8; ++ct_) {                               \
                uint2 v2_ = make_uint2(pk2(acc_[ct_][0], acc_[ct_][1]),       \
                                       pk2(acc_[ct_][2], acc_[ct_][3]));      \
                *reinterpret_cast<uint2*>(yp_ + ct_ * 8) = v2_;               \
            }                                                                 \
        }                                                                     \
    }

    int rt = wave;
    if (rt >= ntiles) return;
    float4 bufA[8], bufB[8];
    LOADX(rt, bufA);
    while (true) {
        int nxt = rt + nwaves;
        if (nxt < ntiles) {
            LOADX(nxt, bufB);
            COMPUTE(rt, bufA);
            rt = nxt;
            nxt = rt + nwaves;
            if (nxt < ntiles) {
                LOADX(nxt, bufA);
                COMPUTE(rt, bufB);
                rt = nxt;
            } else { COMPUTE(rt, bufB); break; }
        } else { COMPUTE(rt, bufA); break; }
    }
#undef LOADX
#undef COMPUTE
}

// ---------------------------------------------------------------------------
// Kernel 2: build CSR row_ptr from sorted edge_row.
// ---------------------------------------------------------------------------
__global__ __launch_bounds__(256) void build_rowptr_kernel(
    const int* __restrict__ row, int* __restrict__ ptr, int n_edges, int n_nodes)
{
    int e = blockIdx.x * blockDim.x + threadIdx.x;
    if (e > n_edges) return;
    int lo, hi;                     // set ptr[r] = e for r in (lo, hi]
    if (e == 0)            { lo = -1;               hi = row[0];   }
    else if (e == n_edges) { lo = row[n_edges - 1]; hi = n_nodes;  }
    else {
        lo = row[e - 1];
        hi = row[e];
        if (lo == hi) return;
    }
    for (int r = lo + 1; r <= hi; ++r) ptr[r] = e;
}

// ---------------------------------------------------------------------------
// Kernel 3: out[r,:] = sum_e val[e] * y[col[e],:]   (bf16 gather, fp32 acc)
// One wave per row, lane owns 1 packed uint (2 cols). 8-edge batches,
// explicitly double-buffered: 16 gathers in flight steady-state, low VGPR
// (no readfirstlane -> low SGPR) for full occupancy.
// ---------------------------------------------------------------------------
#define EUNR 8

__global__ __launch_bounds__(256) void spmm_kernel(
    const unsigned* __restrict__ yb, const int* __restrict__ ptr,
    const int* __restrict__ col, const float* __restrict__ val,
    float2* __restrict__ out2, int n_nodes)
{
    int gid  = blockIdx.x * blockDim.x + threadIdx.x;
    int r    = gid >> 6;            // one wave per row
    int lane = threadIdx.x & 63;
    if (r >= n_nodes) return;

    const int s = ptr[r];
    const int e = ptr[r + 1];

    float ax = 0.f, ay = 0.f;
    const int nb = (e - s) >> 3;    // full 8-batches
    int i = s + (nb << 3);          // tail start

    int      cA[EUNR], cB[EUNR];
    float    vA[EUNR], vB[EUNR];
    unsigned uA[EUNR], uB[EUNR];

#define ISSUE(tb_, C_, V_, U_)                                     \
    {                                                              \
        const int base_ = s + ((tb_) << 3);                        \
        _Pragma("unroll")                                          \
        for (int k_ = 0; k_ < EUNR; ++k_) {                        \
            C_[k_] = col[base_ + k_];                              \
            V_[k_] = val[base_ + k_];                              \
        }                                                          \
        _Pragma("unroll")                                          \
        for (int k_ = 0; k_ < EUNR; ++k_)                          \
            U_[k_] = yb[(size_t)C_[k_] * D2U + lane];              \
    }
#define CONSUME(V_, U_)                                            \
    {                                                              \
        _Pragma("unroll")                                          \
        for (int k_ = 0; k_ < EUNR; ++k_) {                        \
            ax += V_[k_] * bflo(U_[k_]);                           \
            ay += V_[k_] * bfhi(U_[k_]);                           \
        }                                                          \
    }

    if (nb > 0) {
        ISSUE(0, cA, vA, uA);
        int tb = 0;
        while (tb + 1 < nb) {
            ISSUE(tb + 1, cB, vB, uB);
            CONSUME(vA, uA);
            ++tb;
            if (tb + 1 < nb) {
                ISSUE(tb + 1, cA, vA, uA);
                CONSUME(vB, uB);
                ++tb;
            } else {
                CONSUME(vB, uB);
                ++tb;
            }
        }
        if (tb < nb) CONSUME(vA, uA);
    }
#undef ISSUE
#undef CONSUME

    // tail (< 8 edges): 4-unrolled then scalar
    for (; i + 4 <= e; i += 4) {
        const int   c0 = col[i],     c1 = col[i + 1], c2 = col[i + 2], c3 = col[i + 3];
        const float v0 = val[i],     v1 = val[i + 1], v2 = val[i + 2], v3 = val[i + 3];
        const unsigned u0 = yb[(size_t)c0 * D2U + lane];
        const unsigned u1 = yb[(size_t)c1 * D2U + lane];
        const unsigned u2 = yb[(size_t)c2 * D2U + lane];
        const unsigned u3 = yb[(size_t)c3 * D2U + lane];
        ax += v0 * bflo(u0); ay += v0 * bfhi(u0);
        ax += v1 * bflo(u1); ay += v1 * bfhi(u1);
        ax += v2 * bflo(u2); ay += v2 * bfhi(u2);
        ax += v3 * bflo(u3); ay += v3 * bfhi(u3);
    }
    for (; i < e; ++i) {
        const int      c = col[i];
        const float    v = val[i];
        const unsigned u = yb[(size_t)c * D2U + lane];
        ax += v * bflo(u); ay += v * bfhi(u);
    }

    f32x2 o;
    o.x = ax; o.y = ay;
    __builtin_nontemporal_store(o,
        reinterpret_cast<f32x2*>(out2 + (size_t)r * D2U + lane));
}

// ---------------------------------------------------------------------------
extern "C" void kernel_launch(void* const* d_in, const int* in_sizes, int n_in,
                              void* d_out, int out_size, void* d_ws, size_t ws_size,
                              hipStream_t stream)
{
    const float* x        = (const float*)d_in[0];
    const int*   edge_row = (const int*)  d_in[1];
    const int*   edge_col = (const int*)  d_in[2];
    const float* edge_val = (const float*)d_in[3];
    const float* W        = (const float*)d_in[4];
    float*       out      = (float*)d_out;

    const int n_nodes = in_sizes[0] / D;
    const int n_edges = in_sizes[1];
    const int ntiles  = (n_nodes + 15) / 16;

    // workspace layout: y_bf16 [n_nodes*D2U uint] | row_ptr [(n_nodes+1) i32]
    unsigned* y   = (unsigned*)d_ws;
    int*      ptr = (int*)((char*)d_ws + (size_t)n_nodes * D2U * sizeof(unsigned));

    // 1) y = bf16(x @ W)  (MFMA)
    gemm_mfma_kernel<<<512, 256, 0, stream>>>(x, W, y, n_nodes, ntiles);

    // 2) row_ptr
    {
        int blocks = (n_edges + 1 + 255) / 256;
        build_rowptr_kernel<<<blocks, 256, 0, stream>>>(edge_row, ptr, n_edges, n_nodes);
    }
    // 3) out = A @ y   (one wave per row)
    {
        int rows_per_block = 256 / 64;
        int blocks = (n_nodes + rows_per_block - 1) / rows_per_block;
        spmm_kernel<<<blocks, 256, 0, stream>>>(y, ptr, edge_col, edge_val,
                                                (float2*)out, n_nodes);
    }
}